// Round 5
// baseline (322.741 us; speedup 1.0000x reference)
//
#include <hip/hip_runtime.h>

// DACGLSTMExpert: 18432 independent CGLSTM sequences, T=120, H=32, DIN=1.
// Lane l of each 32-lane group = hidden index; 2 sequences per wave64.
// h broadcast via LDS (8 uniform ds_read_b128 = HW broadcast per group).
// Inner matvec: explicit inline-asm v_pk_fma_f32 with "v" constraints to
// force the 128 per-lane weight floats into ARCH VGPRs (round-3 counters
// showed the compiler put them in AGPRs: VGPR_Count=84, occupancy 2.4/SIMD,
// ~160 extra VALU ops/step from v_accvgpr_read).
// o-gate is dead code in the reference and skipped (validated rounds 1/3).

constexpr int T = 120;
constexpr int H = 32;
constexpr int NSEQ = 2048 * 9;        // 18432
constexpr int SEQ_PER_BLOCK = 8;      // 256 threads / 32 lanes per seq
constexpr int BLOCK = 256;

typedef float v2f __attribute__((ext_vector_type(2)));
typedef float v4f __attribute__((ext_vector_type(4)));

#define LOG2E 1.4426950408889634f

__device__ __forceinline__ float fast_rcp(float x) {
    return __builtin_amdgcn_rcpf(x);
}
__device__ __forceinline__ float fast_exp2(float x) {
    return __builtin_amdgcn_exp2f(x);
}
__device__ __forceinline__ float sigmoid_f(float x) {
    return fast_rcp(1.0f + fast_exp2(-LOG2E * x));
}
__device__ __forceinline__ float tanh_f(float x) {
    return 1.0f - 2.0f * fast_rcp(1.0f + fast_exp2(2.0f * LOG2E * x));
}

// D = S0*S1 + S2 with all operands forced into arch VGPRs.
#define PKFMA(acc, hv, wv) \
    asm("v_pk_fma_f32 %0, %1, %2, %0" : "+v"(acc) : "v"(hv), "v"(wv))

__global__ __launch_bounds__(BLOCK, 2) void cglstm_kernel(
    const float* __restrict__ x,      // [NSEQ, T]
    const float* __restrict__ W_ih,   // [4H, 1]
    const float* __restrict__ W_hh,   // [4H, H]
    const float* __restrict__ b_ih,   // [4H]
    const float* __restrict__ b_hh,   // [4H]
    const float* __restrict__ W_cg_x, // [H, 1]
    const float* __restrict__ W_cg_h, // [H, H]
    const float* __restrict__ b_cg,   // [H]
    float* __restrict__ out)          // [NSEQ, H]
{
    __shared__ float xs[SEQ_PER_BLOCK * T];   // 3840 B
    __shared__ float hs[SEQ_PER_BLOCK * H];   // 1024 B

    const int tid = threadIdx.x;
    const int l   = tid & 31;          // hidden index within sequence
    const int sib = tid >> 5;          // sequence-in-block 0..7
    const int seq = blockIdx.x * SEQ_PER_BLOCK + sib;

    // --- stage this block's x rows into LDS (fully coalesced) ---
    const float* xblk = x + (size_t)blockIdx.x * SEQ_PER_BLOCK * T;
    for (int i = tid; i < SEQ_PER_BLOCK * T; i += BLOCK)
        xs[i] = xblk[i];

    // --- per-lane weights in registers, packed as (even j, odd j) pairs ---
    v2f wi2[H / 2], wf2[H / 2], wg2[H / 2], wc2[H / 2];
    {
        const v4f* ri = (const v4f*)(W_hh + (size_t)(0 * H + l) * H);
        const v4f* rf = (const v4f*)(W_hh + (size_t)(1 * H + l) * H);
        const v4f* rg = (const v4f*)(W_hh + (size_t)(2 * H + l) * H);
        const v4f* rc = (const v4f*)(W_cg_h + (size_t)l * H);
        #pragma unroll
        for (int q = 0; q < H / 4; ++q) {
            v4f vi = ri[q], vf = rf[q], vg = rg[q], vc = rc[q];
            wi2[2*q]   = __builtin_shufflevector(vi, vi, 0, 1);
            wi2[2*q+1] = __builtin_shufflevector(vi, vi, 2, 3);
            wf2[2*q]   = __builtin_shufflevector(vf, vf, 0, 1);
            wf2[2*q+1] = __builtin_shufflevector(vf, vf, 2, 3);
            wg2[2*q]   = __builtin_shufflevector(vg, vg, 0, 1);
            wg2[2*q+1] = __builtin_shufflevector(vg, vg, 2, 3);
            wc2[2*q]   = __builtin_shufflevector(vc, vc, 0, 1);
            wc2[2*q+1] = __builtin_shufflevector(vc, vc, 2, 3);
        }
    }
    const float wi_i = W_ih[0 * H + l];
    const float wi_f = W_ih[1 * H + l];
    const float wi_g = W_ih[2 * H + l];
    const float wcx  = W_cg_x[l];
    const float bi   = b_ih[0 * H + l] + b_hh[0 * H + l];
    const float bf   = b_ih[1 * H + l] + b_hh[1 * H + l];
    const float bg   = b_ih[2 * H + l] + b_hh[2 * H + l];
    const float bc   = b_cg[l];

    // initial h = 0 (each wave owns its groups' slots; barrier covers xs)
    hs[sib * H + l] = 0.0f;
    __syncthreads();

    float c = 0.0f;
    float h_out = 0.0f;
    const v4f* xrow4 = (const v4f*)(xs + sib * T);      // T=120, 16B-aligned
    const v4f* hp = (const v4f*)(hs + sib * H);         // 8 x 16B
    float* hw = hs + sib * H + l;

    #pragma unroll 1
    for (int t4 = 0; t4 < T / 4; ++t4) {
        const v4f xq = xrow4[t4];   // 4 timesteps of x, one uniform b128 read
        #pragma unroll
        for (int tt = 0; tt < 4; ++tt) {
            const float xt = xq[tt];

            // load the group's 32 h values (uniform-address broadcast reads)
            v4f h4[8];
            #pragma unroll
            for (int q = 0; q < 8; ++q) h4[q] = hp[q];

            v2f aI = v2f{fmaf(xt, wi_i, bi), 0.0f};
            v2f aF = v2f{fmaf(xt, wi_f, bf), 0.0f};
            v2f aG = v2f{fmaf(xt, wi_g, bg), 0.0f};
            v2f aC = v2f{fmaf(xt, wcx,  bc), 0.0f};

            #pragma unroll
            for (int q = 0; q < 8; ++q) {
                v2f h01 = __builtin_shufflevector(h4[q], h4[q], 0, 1);
                v2f h23 = __builtin_shufflevector(h4[q], h4[q], 2, 3);
                PKFMA(aI, h01, wi2[2*q]);
                PKFMA(aF, h01, wf2[2*q]);
                PKFMA(aG, h01, wg2[2*q]);
                PKFMA(aC, h01, wc2[2*q]);
                PKFMA(aI, h23, wi2[2*q+1]);
                PKFMA(aF, h23, wf2[2*q+1]);
                PKFMA(aG, h23, wg2[2*q+1]);
                PKFMA(aC, h23, wc2[2*q+1]);
            }

            const float ig = sigmoid_f(aI.x + aI.y);
            const float fg = sigmoid_f(aF.x + aF.y);
            const float gg = tanh_f(aG.x + aG.y);
            const float cg = sigmoid_f(aC.x + aC.y);   // contextual gate (prev h)
            c = fmaf(fg, c, ig * gg);
            h_out = cg * tanh_f(c);                    // o-gate dead in reference

            *hw = h_out;   // publish for next step (same-wave consumers only)
        }
    }

    out[(size_t)seq * H + l] = h_out;
}

extern "C" void kernel_launch(void* const* d_in, const int* in_sizes, int n_in,
                              void* d_out, int out_size, void* d_ws, size_t ws_size,
                              hipStream_t stream) {
    const float* x      = (const float*)d_in[0];
    const float* W_ih   = (const float*)d_in[1];
    const float* W_hh   = (const float*)d_in[2];
    const float* b_ih   = (const float*)d_in[3];
    const float* b_hh   = (const float*)d_in[4];
    const float* W_cg_x = (const float*)d_in[5];
    const float* W_cg_h = (const float*)d_in[6];
    const float* b_cg   = (const float*)d_in[7];
    float* out = (float*)d_out;

    const int grid = NSEQ / SEQ_PER_BLOCK;   // 2304
    cglstm_kernel<<<grid, BLOCK, 0, stream>>>(
        x, W_ih, W_hh, b_ih, b_hh, W_cg_x, W_cg_h, b_cg, out);
}

// Round 7
// 279.628 us; speedup vs baseline: 1.1542x; 1.1542x over previous
//
#include <hip/hip_runtime.h>

// DACGLSTMExpert: 18432 independent CGLSTM sequences, T=120, H=32, DIN=1.
// Lane l of each 32-lane group = hidden index; 2 sequences per wave64.
//
// Round-5 lesson: the allocator "spills" big per-lane arrays to AGPRs to
// chase occupancy (VGPR_Count stayed 84/88); VALU can't read AGPRs so every
// use pays a v_accvgpr_read (~128 moves/step). Fix: make the weights FIT
// the arch budget: f16 pairs (64 VGPRs instead of 128) consumed by
// v_dot2_f32_f16 (2 MACs/instr, f32 accumulate), and pin the allocator with
// amdgpu_waves_per_eu(4,4) so spilling-for-occupancy has no payoff.
// h is broadcast via LDS as f16: 4 uniform ds_read_b128 per step.
// o-gate is dead code in the reference and skipped (validated rounds 1/3/5).

constexpr int T = 120;
constexpr int H = 32;
constexpr int NSEQ = 2048 * 9;        // 18432
constexpr int SEQ_PER_BLOCK = 8;      // 256 threads / 32 lanes per seq
constexpr int BLOCK = 256;

typedef _Float16 f16;
typedef _Float16 h2 __attribute__((ext_vector_type(2)));
typedef float v4f __attribute__((ext_vector_type(4)));
typedef unsigned int u32;

#define LOG2E 1.4426950408889634f

__device__ __forceinline__ float fast_rcp(float x) {
    return __builtin_amdgcn_rcpf(x);
}
__device__ __forceinline__ float fast_exp2(float x) {
    return __builtin_amdgcn_exp2f(x);
}
// sigmoid(x) = 1 / (1 + 2^(-x*log2e))
__device__ __forceinline__ float sigmoid_f(float x) {
    return fast_rcp(1.0f + fast_exp2(-LOG2E * x));
}
// tanh(x) = 1 - 2/(2^(2x*log2e) + 1)
__device__ __forceinline__ float tanh_f(float x) {
    return fmaf(-2.0f, fast_rcp(1.0f + fast_exp2(2.0f * LOG2E * x)), 1.0f);
}

// acc += dot2(hv, wv) with f32 accumulate (v_dot2_f32_f16).
#if __has_builtin(__builtin_amdgcn_fdot2)
#define DOT2(acc, hv, wv) (acc) = __builtin_amdgcn_fdot2((hv), (wv), (acc), false)
#else
#define DOT2(acc, hv, wv) asm("v_dot2_f32_f16 %0, %1, %2, %0" \
                              : "+v"(acc) : "v"(hv), "v"(wv))
#endif

// One h-pair (32-bit word) against the 4 gate weight-pairs at index idx.
#define DOTBLK(word, idx)                                \
    {                                                    \
        const h2 hv = __builtin_bit_cast(h2, (word));    \
        DOT2(aI, hv, wi2[idx]);                          \
        DOT2(aF, hv, wf2[idx]);                          \
        DOT2(aG, hv, wg2[idx]);                          \
        DOT2(aC, hv, wc2[idx]);                          \
    }

__global__ __launch_bounds__(BLOCK)
__attribute__((amdgpu_waves_per_eu(4, 4)))
void cglstm_kernel(
    const float* __restrict__ x,      // [NSEQ, T]
    const float* __restrict__ W_ih,   // [4H, 1]
    const float* __restrict__ W_hh,   // [4H, H]
    const float* __restrict__ b_ih,   // [4H]
    const float* __restrict__ b_hh,   // [4H]
    const float* __restrict__ W_cg_x, // [H, 1]
    const float* __restrict__ W_cg_h, // [H, H]
    const float* __restrict__ b_cg,   // [H]
    float* __restrict__ out)          // [NSEQ, H]
{
    __shared__ float xs[SEQ_PER_BLOCK * T];                 // 3840 B
    __shared__ __align__(16) f16 hs[SEQ_PER_BLOCK * H];     // 512 B

    const int tid = threadIdx.x;
    const int l   = tid & 31;          // hidden index within sequence
    const int sib = tid >> 5;          // sequence-in-block 0..7
    const int seq = blockIdx.x * SEQ_PER_BLOCK + sib;

    // --- stage this block's x rows into LDS (fully coalesced) ---
    const float* xblk = x + (size_t)blockIdx.x * SEQ_PER_BLOCK * T;
    for (int i = tid; i < SEQ_PER_BLOCK * T; i += BLOCK)
        xs[i] = xblk[i];

    // --- per-lane weights as f16 pairs: 4 gates x 16 pairs = 64 VGPRs ---
    h2 wi2[H / 2], wf2[H / 2], wg2[H / 2], wc2[H / 2];
    {
        const v4f* ri = (const v4f*)(W_hh + (size_t)(0 * H + l) * H);
        const v4f* rf = (const v4f*)(W_hh + (size_t)(1 * H + l) * H);
        const v4f* rg = (const v4f*)(W_hh + (size_t)(2 * H + l) * H);
        const v4f* rc = (const v4f*)(W_cg_h + (size_t)l * H);
        #pragma unroll
        for (int q = 0; q < H / 4; ++q) {
            v4f vi = ri[q], vf = rf[q], vg = rg[q], vc = rc[q];
            wi2[2*q]   = h2{(f16)vi.x, (f16)vi.y};
            wi2[2*q+1] = h2{(f16)vi.z, (f16)vi.w};
            wf2[2*q]   = h2{(f16)vf.x, (f16)vf.y};
            wf2[2*q+1] = h2{(f16)vf.z, (f16)vf.w};
            wg2[2*q]   = h2{(f16)vg.x, (f16)vg.y};
            wg2[2*q+1] = h2{(f16)vg.z, (f16)vg.w};
            wc2[2*q]   = h2{(f16)vc.x, (f16)vc.y};
            wc2[2*q+1] = h2{(f16)vc.z, (f16)vc.w};
        }
    }
    const float wi_i = W_ih[0 * H + l];
    const float wi_f = W_ih[1 * H + l];
    const float wi_g = W_ih[2 * H + l];
    const float wcx  = W_cg_x[l];
    const float bi   = b_ih[0 * H + l] + b_hh[0 * H + l];
    const float bf   = b_ih[1 * H + l] + b_hh[1 * H + l];
    const float bg   = b_ih[2 * H + l] + b_hh[2 * H + l];
    const float bc   = b_cg[l];

    // initial h = 0 (each 32-lane group owns its own slots)
    hs[sib * H + l] = (f16)0.0f;
    __syncthreads();

    float c = 0.0f;
    float h_out = 0.0f;
    const v4f* xrow4 = (const v4f*)(xs + sib * T);     // T=120, 16B-aligned
    const uint4* hp4 = (const uint4*)(hs + sib * H);   // 4 x 16B, uniform addr
    f16* hw = hs + sib * H + l;

    #pragma unroll 1
    for (int t4 = 0; t4 < T / 4; ++t4) {
        const v4f xq = xrow4[t4];   // 4 timesteps of x, one uniform b128 read
        #pragma unroll
        for (int tt = 0; tt < 4; ++tt) {
            const float xt = xq[tt];

            // group's 32 h values as f16 (uniform-address broadcast reads)
            const uint4 hr0 = hp4[0];
            const uint4 hr1 = hp4[1];
            const uint4 hr2 = hp4[2];
            const uint4 hr3 = hp4[3];

            float aI = fmaf(xt, wi_i, bi);
            float aF = fmaf(xt, wi_f, bf);
            float aG = fmaf(xt, wi_g, bg);
            float aC = fmaf(xt, wcx,  bc);

            DOTBLK(hr0.x,  0) DOTBLK(hr0.y,  1) DOTBLK(hr0.z,  2) DOTBLK(hr0.w,  3)
            DOTBLK(hr1.x,  4) DOTBLK(hr1.y,  5) DOTBLK(hr1.z,  6) DOTBLK(hr1.w,  7)
            DOTBLK(hr2.x,  8) DOTBLK(hr2.y,  9) DOTBLK(hr2.z, 10) DOTBLK(hr2.w, 11)
            DOTBLK(hr3.x, 12) DOTBLK(hr3.y, 13) DOTBLK(hr3.z, 14) DOTBLK(hr3.w, 15)

            const float ig = sigmoid_f(aI);
            const float fg = sigmoid_f(aF);
            const float gg = tanh_f(aG);
            const float cg = sigmoid_f(aC);   // contextual gate (prev h)
            c = fmaf(fg, c, ig * gg);
            h_out = cg * tanh_f(c);           // o-gate dead in reference

            *hw = (f16)h_out;   // publish for next step (same-wave consumers)
        }
    }

    out[(size_t)seq * H + l] = h_out;
}

extern "C" void kernel_launch(void* const* d_in, const int* in_sizes, int n_in,
                              void* d_out, int out_size, void* d_ws, size_t ws_size,
                              hipStream_t stream) {
    const float* x      = (const float*)d_in[0];
    const float* W_ih   = (const float*)d_in[1];
    const float* W_hh   = (const float*)d_in[2];
    const float* b_ih   = (const float*)d_in[3];
    const float* b_hh   = (const float*)d_in[4];
    const float* W_cg_x = (const float*)d_in[5];
    const float* W_cg_h = (const float*)d_in[6];
    const float* b_cg   = (const float*)d_in[7];
    float* out = (float*)d_out;

    const int grid = NSEQ / SEQ_PER_BLOCK;   // 2304
    cglstm_kernel<<<grid, BLOCK, 0, stream>>>(
        x, W_ih, W_hh, b_ih, b_hh, W_cg_x, W_cg_h, b_cg, out);
}